// Round 1
// baseline (384.759 us; speedup 1.0000x reference)
//
#include <hip/hip_runtime.h>

typedef float v2f __attribute__((ext_vector_type(2)));

#define LYS 11
#define LXS 110

__global__ __launch_bounds__(256, 4)
void gridnet_kernel(const float* __restrict__ W,
                    const float* __restrict__ Bias,
                    const float* __restrict__ Rs,
                    const float* __restrict__ X,
                    float* __restrict__ Y)
{
    __shared__ float blk[10 * LXS + 8];   // 10x10x10 block, strides 110/11/1 (odd to spread banks)
    __shared__ float4 red4[4];
    __shared__ float2 red2[4];

    const int tid = threadIdx.x;
    const int lz  = (tid & 3) << 1;        // z pair base (0,2,4,6)
    const int ly  = (tid >> 2) & 7;
    const int lx  = tid >> 5;
    const int wave = tid >> 6;
    const int lane = tid & 63;

    const int bid   = blockIdx.x;
    const int batch = bid >> 9;
    const int r     = bid & 511;
    const int gm0 = (r >> 6) << 3;
    const int gn0 = ((r >> 3) & 7) << 3;
    const int gk0 = (r & 7) << 3;

    const float* xb = X + ((size_t)batch << 18);

    // ---- load 10x10x10 block (zero-padded halo) into LDS; accumulate total sums ----
    float s_all = 0.f, q_all = 0.f;
    for (int i = tid; i < 1000; i += 256) {
        int ix = i / 100;
        int rem = i - ix * 100;
        int iy = rem / 10;
        int iz = rem - iy * 10;
        int m = gm0 + ix - 1, n = gn0 + iy - 1, k = gk0 + iz - 1;
        float v = 0.f;
        if ((unsigned)m < 64u && (unsigned)n < 64u && (unsigned)k < 64u)
            v = xb[(m << 12) + (n << 6) + k];
        blk[ix * LXS + iy * LYS + iz] = v;
        s_all += v;
        q_all += v * v;
    }

    // ---- per-thread params: 27 taps x 2 outputs, kept in registers for all 8 iters ----
    const int gm = gm0 + lx, gn = gn0 + ly, gk = gk0 + lz;
    const size_t ofs = ((size_t)gm << 12) + (gn << 6) + gk;

    v2f w2[27];
    v2f sumw = {0.f, 0.f};
    #pragma unroll
    for (int t = 0; t < 27; ++t) {
        v2f wv = *(const v2f*)(W + ((size_t)t << 18) + ofs);
        w2[t] = wv;
        sumw += wv;
    }
    const v2f bias2 = *(const v2f*)(Bias + ofs);
    const v2f rsc2  = *(const v2f*)(Rs + ofs);

    __syncthreads();

    const int ip = (lx + 1) * LXS + (ly + 1) * LYS + (lz + 1);
    float cur0 = blk[ip];
    float cur1 = blk[ip + 1];

    // ---- one-time full reduction: total sums + interior sums -> frozen halo sums ----
    float a0 = s_all, a1 = q_all;
    float a2 = cur0 + cur1, a3 = cur0 * cur0 + cur1 * cur1;
    #pragma unroll
    for (int off = 32; off; off >>= 1) {
        a0 += __shfl_xor(a0, off);
        a1 += __shfl_xor(a1, off);
        a2 += __shfl_xor(a2, off);
        a3 += __shfl_xor(a3, off);
    }
    if (lane == 0) red4[wave] = make_float4(a0, a1, a2, a3);
    __syncthreads();
    float S_all = 0.f, Q_all = 0.f, Si = 0.f, Qi = 0.f;
    #pragma unroll
    for (int wv = 0; wv < 4; ++wv) {
        float4 t4 = red4[wv];
        S_all += t4.x; Q_all += t4.y; Si += t4.z; Qi += t4.w;
    }
    const float halo_s = S_all - Si;
    const float halo_q = Q_all - Qi;

    const float inv_n = 1.0f / 1000.0f;

    #pragma unroll 1
    for (int it = 0; it < 8; ++it) {
        // normalization stats: frozen halo sums + register-resident interior sums
        float mean = (halo_s + Si) * inv_n;
        float e2   = (halo_q + Qi) * inv_n;
        float istd = rsqrtf(e2 - mean * mean + 1e-5f);

        // 27-tap dot on RAW values; normalization folded in afterwards:
        //   sum_t w_t*(v_t-mean)*istd = istd*(rawdot - mean*sumw)
        v2f dot = {0.f, 0.f};
        #pragma unroll
        for (int dx = 0; dx < 3; ++dx) {
            #pragma unroll
            for (int dy = 0; dy < 3; ++dy) {
                const float* p = &blk[(lx + dx) * LXS + (ly + dy) * LYS + lz];
                float n0 = p[0], n1 = p[1], n2 = p[2], n3 = p[3];
                int t = dx * 9 + dy * 3;
                v2f A;
                A.x = n0; A.y = n1; dot += A * w2[t];
                A.x = n1; A.y = n2; dot += A * w2[t + 1];
                A.x = n2; A.y = n3; dot += A * w2[t + 2];
            }
        }
        v2f dn = (dot - mean * sumw) * istd;
        v2f u = dn + bias2;
        float s0 = u.x / (1.f + __expf(-u.x));
        float s1 = u.y / (1.f + __expf(-u.y));
        cur0 += rsc2.x * s0;
        cur1 += rsc2.y * s1;

        __syncthreads();                 // all neighbor reads of iter `it` complete
        blk[ip] = cur0;
        blk[ip + 1] = cur1;

        // reduce interior sums for next iteration (values are in registers)
        float b0 = cur0 + cur1, b1 = cur0 * cur0 + cur1 * cur1;
        #pragma unroll
        for (int off = 32; off; off >>= 1) {
            b0 += __shfl_xor(b0, off);
            b1 += __shfl_xor(b1, off);
        }
        if (lane == 0) red2[wave] = make_float2(b0, b1);
        __syncthreads();                 // block writes + partial sums visible
        Si = red2[0].x + red2[1].x + red2[2].x + red2[3].x;
        Qi = red2[0].y + red2[1].y + red2[2].y + red2[3].y;
    }

    *(v2f*)(Y + ((size_t)batch << 18) + ofs) = (v2f){cur0, cur1};
}

extern "C" void kernel_launch(void* const* d_in, const int* in_sizes, int n_in,
                              void* d_out, int out_size, void* d_ws, size_t ws_size,
                              hipStream_t stream) {
    const float* W = (const float*)d_in[0];   // (27,64,64,64)
    const float* B = (const float*)d_in[1];   // (64,64,64)
    const float* R = (const float*)d_in[2];   // (64,64,64)
    const float* X = (const float*)d_in[3];   // (16,64,64,64)
    float* Y = (float*)d_out;

    int n_batch = in_sizes[3] >> 18;          // 64^3 per sample
    dim3 grid(n_batch * 512), block(256);
    hipLaunchKernelGGL(gridnet_kernel, grid, block, 0, stream, W, B, R, X, Y);
}

// Round 2
// 187.602 us; speedup vs baseline: 2.0509x; 2.0509x over previous
//
#include <hip/hip_runtime.h>

#define LYS 12
#define LXS 120   // 10 * LYS; both strides ≡ 0 mod 4 words -> aligned b128 line reads

__global__ __launch_bounds__(128, 2)
void gridnet_kernel(const float* __restrict__ W,
                    const float* __restrict__ Bias,
                    const float* __restrict__ Rs,
                    const float* __restrict__ X,
                    float* __restrict__ Y,
                    int n_batch)
{
    __shared__ __align__(16) float blk[10 * LXS];
    __shared__ float4 red4[2];
    __shared__ float2 red2[2];

    const int tid  = threadIdx.x;
    const int h    = tid & 1;           // z-half: this thread owns outputs z = 4h..4h+3
    const int ly   = (tid >> 1) & 7;
    const int lx   = tid >> 4;
    const int wave = tid >> 6;          // 0..1
    const int lane = tid & 63;

    const int bid   = blockIdx.x;
    const int r     = bid / n_batch;    // spatial block index 0..511
    const int batch = bid - r * n_batch; // batch fast => 16 weight-sharers adjacent in dispatch
    const int gm0 = (r >> 6) << 3;
    const int gn0 = ((r >> 3) & 7) << 3;
    const int gk0 = (r & 7) << 3;

    const float* xb = X + ((size_t)batch << 18);

    // ---- stage 10x10x10 raw block (zero-padded halo) into LDS; total sums on the fly ----
    float s_all = 0.f, q_all = 0.f;
    for (int i = tid; i < 1000; i += 128) {
        int ix = i / 100;
        int rem = i - ix * 100;
        int iy = rem / 10;
        int iz = rem - iy * 10;
        int m = gm0 + ix - 1, n = gn0 + iy - 1, k = gk0 + iz - 1;
        float v = 0.f;
        if ((unsigned)m < 64u && (unsigned)n < 64u && (unsigned)k < 64u)
            v = xb[(m << 12) + (n << 6) + k];
        blk[ix * LXS + iy * LYS + iz] = v;
        s_all += v;
        q_all += v * v;
    }

    // ---- per-thread params: 27 taps x 4 z-outputs, pinned in VGPRs for all 8 iters ----
    const int gm = gm0 + lx, gn = gn0 + ly, gk = gk0 + 4 * h;
    const size_t ofs = ((size_t)gm << 12) + (gn << 6) + gk;

    float4 w4[27];
    float sw0 = 0.f, sw1 = 0.f, sw2 = 0.f, sw3 = 0.f;
    #pragma unroll
    for (int t = 0; t < 27; ++t) {
        w4[t] = *(const float4*)(W + ((size_t)t << 18) + ofs);
        sw0 += w4[t].x; sw1 += w4[t].y; sw2 += w4[t].z; sw3 += w4[t].w;
    }
    float4 b4 = *(const float4*)(Bias + ofs);
    float4 r4 = *(const float4*)(Rs + ofs);

    // Value barrier: forces weights/params to stay VGPR-resident across the loop
    // (R1 showed the compiler re-issuing these loads every iteration: VGPR=48, 985MB fetch).
    #pragma unroll
    for (int t = 0; t < 27; ++t)
        asm volatile("" : "+v"(w4[t].x), "+v"(w4[t].y), "+v"(w4[t].z), "+v"(w4[t].w));
    asm volatile("" : "+v"(b4.x), "+v"(b4.y), "+v"(b4.z), "+v"(b4.w));
    asm volatile("" : "+v"(r4.x), "+v"(r4.y), "+v"(r4.z), "+v"(r4.w));
    asm volatile("" : "+v"(sw0), "+v"(sw1), "+v"(sw2), "+v"(sw3));

    __syncthreads();

    const int ip = (lx + 1) * LXS + (ly + 1) * LYS + (4 * h + 1);
    float c0 = blk[ip], c1 = blk[ip + 1], c2 = blk[ip + 2], c3 = blk[ip + 3];

    // ---- one-time full reduction: total + interior sums -> frozen halo sums ----
    float a0 = s_all, a1 = q_all;
    float a2 = c0 + c1 + c2 + c3;
    float a3 = c0 * c0 + c1 * c1 + c2 * c2 + c3 * c3;
    #pragma unroll
    for (int off = 32; off; off >>= 1) {
        a0 += __shfl_xor(a0, off);
        a1 += __shfl_xor(a1, off);
        a2 += __shfl_xor(a2, off);
        a3 += __shfl_xor(a3, off);
    }
    if (lane == 0) red4[wave] = make_float4(a0, a1, a2, a3);
    __syncthreads();
    float4 t0 = red4[0], t1 = red4[1];
    const float halo_s = (t0.x + t1.x) - (t0.z + t1.z);
    const float halo_q = (t0.y + t1.y) - (t0.w + t1.w);
    float Si = t0.z + t1.z;
    float Qi = t0.w + t1.w;

    const float inv_n = 1.0f / 1000.0f;

    #pragma unroll 1
    for (int it = 0; it < 8; ++it) {
        float mean = (halo_s + Si) * inv_n;
        float e2   = (halo_q + Qi) * inv_n;
        float istd = rsqrtf(e2 - mean * mean + 1e-5f);

        // 27-tap dot on RAW values; norm folded in: sum w*(v-mean)*istd = istd*(dot - mean*sumw)
        float d0 = 0.f, d1 = 0.f, d2 = 0.f, d3 = 0.f;
        #pragma unroll
        for (int dx = 0; dx < 3; ++dx) {
            #pragma unroll
            for (int dy = 0; dy < 3; ++dy) {
                const float* p = &blk[(lx + dx) * LXS + (ly + dy) * LYS + 4 * h];
                const float4 va = *(const float4*)p;       // ds_read_b128, 16B-aligned
                const float2 vb = *(const float2*)(p + 4); // ds_read_b64
                const int t = (dx * 3 + dy) * 3;
                d0 += va.x * w4[t].x;     d1 += va.y * w4[t].y;
                d2 += va.z * w4[t].z;     d3 += va.w * w4[t].w;
                d0 += va.y * w4[t + 1].x; d1 += va.z * w4[t + 1].y;
                d2 += va.w * w4[t + 1].z; d3 += vb.x * w4[t + 1].w;
                d0 += va.z * w4[t + 2].x; d1 += va.w * w4[t + 2].y;
                d2 += vb.x * w4[t + 2].z; d3 += vb.y * w4[t + 2].w;
            }
        }

        float u0 = (d0 - mean * sw0) * istd + b4.x;
        float u1 = (d1 - mean * sw1) * istd + b4.y;
        float u2 = (d2 - mean * sw2) * istd + b4.z;
        float u3 = (d3 - mean * sw3) * istd + b4.w;
        c0 += r4.x * (u0 / (1.f + __expf(-u0)));
        c1 += r4.y * (u1 / (1.f + __expf(-u1)));
        c2 += r4.z * (u2 / (1.f + __expf(-u2)));
        c3 += r4.w * (u3 / (1.f + __expf(-u3)));

        __syncthreads();                  // all reads of old block complete
        blk[ip]     = c0;
        blk[ip + 1] = c1;
        blk[ip + 2] = c2;
        blk[ip + 3] = c3;

        float b0 = c0 + c1 + c2 + c3;
        float b1 = c0 * c0 + c1 * c1 + c2 * c2 + c3 * c3;
        #pragma unroll
        for (int off = 32; off; off >>= 1) {
            b0 += __shfl_xor(b0, off);
            b1 += __shfl_xor(b1, off);
        }
        if (lane == 0) red2[wave] = make_float2(b0, b1);
        __syncthreads();                  // block writes + partial sums visible
        Si = red2[0].x + red2[1].x;
        Qi = red2[0].y + red2[1].y;
    }

    *(float4*)(Y + ((size_t)batch << 18) + ofs) = make_float4(c0, c1, c2, c3);
}

extern "C" void kernel_launch(void* const* d_in, const int* in_sizes, int n_in,
                              void* d_out, int out_size, void* d_ws, size_t ws_size,
                              hipStream_t stream) {
    const float* W = (const float*)d_in[0];   // (27,64,64,64)
    const float* B = (const float*)d_in[1];   // (64,64,64)
    const float* R = (const float*)d_in[2];   // (64,64,64)
    const float* X = (const float*)d_in[3];   // (16,64,64,64)
    float* Y = (float*)d_out;

    int n_batch = in_sizes[3] >> 18;          // 64^3 per sample
    dim3 grid(512 * n_batch), block(128);
    hipLaunchKernelGGL(gridnet_kernel, grid, block, 0, stream, W, B, R, X, Y, n_batch);
}